// Round 14
// baseline (33.641 us; speedup 1.0000x reference)
//
#include <hip/hip_runtime.h>
#include <hip/hip_bf16.h>
#include <stdint.h>

// ---------------------------------------------------------------------------
// GraphicalBranch: out[r] = relu(x[row_r] @ W_self + (S_{b_r} @ W_nbr) + bias)
//   S_b = sum of the 28 pair-node rows of sample b
//   row_r = b*28 + pidx(pmin,pmax), pidx = 7i - i(i-1)/2 + (j-i-1)  [analytic]
// K1 prep (1536 blks): streaming S-sum + L2-hot gather->Abf | W^T frag-major
// K2 fused GEMM (128x8 blks, 512 THREADS, split-M 8 waves):
//   waves 0-3 -> strips 0-2, waves 4-7 -> strips 3-5; each wave 16 cols.
//   Per-wave regs ~60 -> 8 waves/SIMD -> 32 waves/CU (max TLP; the kernel is
//   TLP-coverage-bound: all scheduling variants R7/R12/R13 nulled, only TLP
//   and per-wave-LDS cuts ever won). A via global_load_lds + XOR swizzle,
//   2-phase dbuf; B direct global->reg frag-major (ws=0 waves load only
//   Wself). Epilogue: out = relu(acc + T[sample] + bias).
// ---------------------------------------------------------------------------

typedef __bf16 bf16_t;
typedef __bf16 bf16x8 __attribute__((ext_vector_type(8)));
typedef __bf16 bf16x4 __attribute__((ext_vector_type(4)));
typedef float  f32x4  __attribute__((ext_vector_type(4)));

#define D_DIM 512
#define NC2   28
#define NOBJ  8
#define MAXREL 10
#define B_SAMP 1024
#define OUTROWS (B_SAMP * MAXREL)

__device__ __forceinline__ void gload_lds16(const void* g, void* l) {
  __builtin_amdgcn_global_load_lds(
      (const __attribute__((address_space(1))) unsigned int*)g,
      (__attribute__((address_space(3))) unsigned int*)l, 16, 0, 0);
}

// --- K1: fused prep (unchanged from R11) -----------------------------------
__global__ __launch_bounds__(256) void prep_kernel(
    const float* __restrict__ x, const float* __restrict__ Wself,
    const float* __restrict__ Wnbr, const int* __restrict__ pairs,
    bf16_t* __restrict__ Sbf, bf16_t* __restrict__ Abf,
    bf16_t* __restrict__ Wsf, bf16_t* __restrict__ Wnf)
{
  const int blk = blockIdx.x, tid = threadIdx.x;
  if (blk < B_SAMP) {
    __shared__ int rel_row[MAXREL];
    __shared__ float4 oddsum[128];
    if (tid < MAXREL) {
      int p0 = pairs[blk * MAXREL * 2 + tid * 2 + 0];
      int p1 = pairs[blk * MAXREL * 2 + tid * 2 + 1];
      int pmin = min(p0, p1), pmax = max(p0, p1);
      rel_row[tid] = 7 * pmin - (pmin * (pmin - 1)) / 2 + (pmax - pmin - 1);
    }
    __syncthreads();

    const int h = tid >> 7, c = tid & 127;        // half, float4-col
    const float4* x4 = (const float4*)(x + (size_t)blk * NC2 * D_DIM);
    float4 a = {0.f, 0.f, 0.f, 0.f};
    #pragma unroll
    for (int rp = 0; rp < NC2 / 2; ++rp) {        // clean streaming sum
      float4 v = x4[(rp * 2 + h) * 128 + c];
      a.x += v.x; a.y += v.y; a.z += v.z; a.w += v.w;
    }
    if (h) oddsum[c] = a;
    __syncthreads();
    if (!h) {
      float4 b = oddsum[c];
      bf16x4 o = { (bf16_t)(a.x + b.x), (bf16_t)(a.y + b.y),
                   (bf16_t)(a.z + b.z), (bf16_t)(a.w + b.w) };
      *(bf16x4*)(Sbf + (size_t)blk * D_DIM + c * 4) = o;
    }
    // gather pass: rows just streamed -> L1/L2 hot
    #pragma unroll
    for (int j = h; j < MAXREL; j += 2) {
      float4 v = x4[rel_row[j] * 128 + c];
      bf16x4 o = { (bf16_t)v.x, (bf16_t)v.y, (bf16_t)v.z, (bf16_t)v.w };
      *(bf16x4*)(Abf + (size_t)(blk * MAXREL + j) * D_DIM + c * 4) = o;
    }
  } else {
    __shared__ float tile[32 * 33];
    const int r = blk - B_SAMP;                   // 0..511
    const float* W  = (r & 256) ? Wnbr : Wself;
    bf16_t*     Wf  = (r & 256) ? Wnf  : Wsf;
    const int piece = r & 255;
    const int tstep = piece & 15, nblk = piece >> 4;
    const int k0 = tstep * 32, n0 = nblk * 32;
    const int tx = tid & 31, ty = tid >> 5;
    #pragma unroll
    for (int i = 0; i < 32; i += 8)
      tile[(ty + i) * 33 + tx] = W[(size_t)(k0 + ty + i) * D_DIM + n0 + tx];
    __syncthreads();
    // frag-major write: cell (cf, tstep) = 64 lanes x 16B; lane l elem e =
    // W[k0 + (l>>4)*8 + e][cf*16 + (l&15)]; stores tid-contiguous 8B
    const int cfl = tid >> 7, rem = tid & 127;
    const int ll = rem >> 1, eh = rem & 1;
    const int kb = (ll >> 4) * 8 + eh * 4;        // k_local base
    const int nl = cfl * 16 + (ll & 15);          // n_local
    bf16x4 o = { (bf16_t)tile[(kb + 0) * 33 + nl], (bf16_t)tile[(kb + 1) * 33 + nl],
                 (bf16_t)tile[(kb + 2) * 33 + nl], (bf16_t)tile[(kb + 3) * 33 + nl] };
    const int cf = nblk * 2 + cfl;
    *(bf16x4*)(Wf + ((size_t)(cf * 16 + tstep) * 64 + ll) * 8 + eh * 4) = o;
  }
}

// --- K2: fused GEMM, 512 threads, split-M 8 waves --------------------------
// Block (bx, by): 8 samples, out rows [bx*80, +80), cols [by*64, +64).
// A strips 0..4 = 80 rel rows (@Wself); strip 5 = 8 S rows dup (@Wnbr -> T).
// Wave w: ws = w>>2 (strip half), wc = w&3 (col quarter, cf = by*4+wc).
//   ws=0 -> strips 0,1,2 (all @Wself); ws=1 -> strips 3,4 (@Wself) + 5 (@Wnbr)
// A-LDS chunks (16B): LDS[row][c] = G[row][c ^ ((row>>1)&3)]  (involution).
#define SA_BYTES 6144              // 96 rows * 64 B

__global__ __launch_bounds__(512) void fused_gemm_kernel(
    const bf16_t* __restrict__ Abf, const bf16_t* __restrict__ Sbf,
    const bf16_t* __restrict__ Wsf, const bf16_t* __restrict__ Wnf,
    const float* __restrict__ bias, float* __restrict__ out)
{
  __shared__ __align__(16) unsigned char pool[2 * SA_BYTES];

  const int tid = threadIdx.x;
  const int w = tid >> 6, l = tid & 63;
  const int ws = w >> 2, wc = w & 3;
  const int kg = l >> 4, lr = l & 15;
  const int n0w = blockIdx.y * 64 + wc * 16;   // wave col base
  const int arow0 = blockIdx.x * 80;
  const int srow0 = blockIdx.x * 8;
  const int cf = blockIdx.y * 4 + wc;          // wave's col-frag index

  // frag-major B streams: step t at +t*512 elems (1KB coalesced per wave)
  const bf16_t* pBs = Wsf + (size_t)cf * 16 * 512 + (size_t)l * 8;
  const bf16_t* pBn = Wnf + (size_t)cf * 16 * 512 + (size_t)l * 8;

  f32x4 acc[3] = {};

  // stage A slab (96 rows x 32 k = 384 x 16B chunks): threads 0..383, 1 each
  auto STAGE = [&](int bsel, int k0) {
    bf16_t* aB = (bf16_t*)(pool + bsel * SA_BYTES);
    if (tid < 384) {
      int row = tid >> 2, ch = tid & 3;
      int sch = ch ^ ((row >> 1) & 3);
      const bf16_t* g = (row < 80)
          ? Abf + (size_t)(arow0 + row) * D_DIM + k0 + sch * 8
          : Sbf + (size_t)(srow0 + (row & 7)) * D_DIM + k0 + sch * 8;
      gload_lds16(g, aB + (size_t)tid * 8);
    }
  };

  const int xorc = (kg ^ ((lr >> 1) & 3)) * 8;   // swizzled chunk -> elem off

#define LOADB(BS, BN, t) do {                                                 \
    BS = *(const bf16x8*)(pBs + (t) * 512);                                   \
    if (ws) BN = *(const bf16x8*)(pBn + (t) * 512);                           \
  } while (0)

#define DO_STEP(bsel, BS, BN) do {                                            \
    const bf16_t* aC = (const bf16_t*)(pool + (bsel) * SA_BYTES);             \
    bf16x8 af[3];                                                             \
    _Pragma("unroll")                                                         \
    for (int s_ = 0; s_ < 3; ++s_)                                            \
      af[s_] = *(const bf16x8*)(aC + ((ws * 48 + s_ * 16) + lr) * 32 + xorc); \
    acc[0] = __builtin_amdgcn_mfma_f32_16x16x32_bf16(af[0], BS, acc[0], 0, 0, 0); \
    acc[1] = __builtin_amdgcn_mfma_f32_16x16x32_bf16(af[1], BS, acc[1], 0, 0, 0); \
    acc[2] = __builtin_amdgcn_mfma_f32_16x16x32_bf16(af[2], ws ? BN : BS, acc[2], 0, 0, 0); \
  } while (0)

  bf16x8 bsX, bnX, bsY, bnY;
  STAGE(0, 0);
  LOADB(bsX, bnX, 0);
  __syncthreads();                               // drains stage + B t=0

  int cur = 0;
  #pragma unroll
  for (int t = 0; t < 16; t += 2) {
    // even step: compute cur with X; prefetch t+1 (A -> cur^1, B -> Y)
    if (t + 1 < 16) {
      STAGE(cur ^ 1, (t + 1) * 32);
      LOADB(bsY, bnY, t + 1);
    }
    DO_STEP(cur, bsX, bnX);
    __syncthreads();                             // prefetch had full step to land
    cur ^= 1;

    // odd step: compute cur with Y; prefetch t+2 (A -> cur^1, B -> X)
    if (t + 2 < 16) {
      STAGE(cur ^ 1, (t + 2) * 32);
      LOADB(bsX, bnX, t + 2);
    }
    DO_STEP(cur, bsY, bnY);
    __syncthreads();
    cur ^= 1;
  }
#undef DO_STEP
#undef LOADB

  // T tile -> LDS (pool reuse; fenced by loop's final barrier).
  // ws=1 waves' acc[2] = S-strip: C row = kg*4+reg (rows 8..15 dup 0..7),
  // col = lr.  Tex[wc][sample][lr]
  float* Tex = (float*)pool;                     // [4][8][20]
  if (ws) {
    #pragma unroll
    for (int reg = 0; reg < 4; ++reg)
      Tex[(wc * 8 + ((kg * 4 + reg) & 7)) * 20 + lr] = acc[2][reg];
  }
  __syncthreads();

  const float bv = bias[n0w + lr];
  const int nstrips = ws ? 2 : 3;                // ws=1: strip 2 is T, no store
  for (int s = 0; s < nstrips; ++s) {
    #pragma unroll
    for (int reg = 0; reg < 4; ++reg) {
      int rloc = ws * 48 + s * 16 + kg * 4 + reg;  // 0..79
      int ls = rloc / MAXREL;                      // local sample 0..7
      float v = acc[s][reg] + Tex[(wc * 8 + ls) * 20 + lr] + bv;
      out[(size_t)(arow0 + rloc) * D_DIM + n0w + lr] = fmaxf(v, 0.0f);
    }
  }
}

extern "C" void kernel_launch(void* const* d_in, const int* in_sizes, int n_in,
                              void* d_out, int out_size, void* d_ws, size_t ws_size,
                              hipStream_t stream) {
  const float* x     = (const float*)d_in[0];   // [28672, 512]
  const float* Wself = (const float*)d_in[1];   // [512, 512]
  const float* Wnbr  = (const float*)d_in[2];   // [512, 512]
  const float* bias  = (const float*)d_in[3];   // [512]
  const int*   pairs = (const int*)d_in[5];     // [1024, 10, 2]

  char* ws = (char*)d_ws;
  size_t off = 0;
  bf16_t* Sbf = (bf16_t*)(ws + off); off += (size_t)B_SAMP * D_DIM * 2;
  bf16_t* Wsf = (bf16_t*)(ws + off); off += (size_t)D_DIM * D_DIM * 2;
  bf16_t* Wnf = (bf16_t*)(ws + off); off += (size_t)D_DIM * D_DIM * 2;
  bf16_t* Abf = (bf16_t*)(ws + off); off += (size_t)OUTROWS * D_DIM * 2;

  prep_kernel<<<B_SAMP + 512, 256, 0, stream>>>(
      x, Wself, Wnbr, pairs, Sbf, Abf, Wsf, Wnf);
  fused_gemm_kernel<<<dim3(OUTROWS / 80, D_DIM / 64), 512, 0, stream>>>(
      Abf, Sbf, Wsf, Wnf, bias, (float*)d_out);
}

// Round 15
// 32.687 us; speedup vs baseline: 1.0292x; 1.0292x over previous
//
#include <hip/hip_runtime.h>
#include <hip/hip_bf16.h>
#include <stdint.h>

// ---------------------------------------------------------------------------
// GraphicalBranch: out[r] = relu(x[row_r] @ W_self + (S_{b_r} @ W_nbr) + bias)
//   S_b = sum of the 28 pair-node rows of sample b
//   row_r = b*28 + pidx(pmin,pmax), pidx = 7i - i(i-1)/2 + (j-i-1)  [analytic]
// K1 prep (1536 blks): streaming S-sum + L2-hot gather->Abf | W^T in
//   MFMA-FRAGMENT-MAJOR layout: cell (cf,t) = 64 lanes x 16B, lane l elem e =
//   W[k = t*32+(l>>4)*8+e][col = cf*16+(l&15)]  -> GEMM B-load is one
//   fully-coalesced dwordx4 per wave (1 KB), no LDS staging for B.
// K2 fused GEMM (128x8 blks, 64-col tiles, 12.3KB LDS):
//   A (5 rel strips + S strip) via global_load_lds + XOR swizzle, dbuf;
//   B direct global->reg from frag-major W (X/Y named-reg dbuf, L2-hot);
//   epilogue out = relu(acc + T[sample] + bias).
// Converged structure (R0-R14 search): wins were grid-2x (R4), +occupancy
// (R6), B-frag-major (R11); nulls: counted-vmcnt (R7), 2-deep pipe (R13),
// split-M max-occupancy (R14), fatter waves (R12); losses: coop grid-sync
// (R8), B-in-reg row-major (R9), A-direct-from-x (R10).
// ---------------------------------------------------------------------------

typedef __bf16 bf16_t;
typedef __bf16 bf16x8 __attribute__((ext_vector_type(8)));
typedef __bf16 bf16x4 __attribute__((ext_vector_type(4)));
typedef float  f32x4  __attribute__((ext_vector_type(4)));

#define D_DIM 512
#define NC2   28
#define NOBJ  8
#define MAXREL 10
#define B_SAMP 1024
#define OUTROWS (B_SAMP * MAXREL)

__device__ __forceinline__ void gload_lds16(const void* g, void* l) {
  __builtin_amdgcn_global_load_lds(
      (const __attribute__((address_space(1))) unsigned int*)g,
      (__attribute__((address_space(3))) unsigned int*)l, 16, 0, 0);
}

// --- K1: fused prep --------------------------------------------------------
// blocks [0,1024):     S[b] = sum of 28 rows (streaming float4) -> bf16;
//                      then gather the 10 rel rows (L1/L2-hot) -> Abf
// blocks [1024,1536):  W -> bf16 fragment-major (256 blocks per matrix)
__global__ __launch_bounds__(256) void prep_kernel(
    const float* __restrict__ x, const float* __restrict__ Wself,
    const float* __restrict__ Wnbr, const int* __restrict__ pairs,
    bf16_t* __restrict__ Sbf, bf16_t* __restrict__ Abf,
    bf16_t* __restrict__ Wsf, bf16_t* __restrict__ Wnf)
{
  const int blk = blockIdx.x, tid = threadIdx.x;
  if (blk < B_SAMP) {
    __shared__ int rel_row[MAXREL];
    __shared__ float4 oddsum[128];
    if (tid < MAXREL) {
      int p0 = pairs[blk * MAXREL * 2 + tid * 2 + 0];
      int p1 = pairs[blk * MAXREL * 2 + tid * 2 + 1];
      int pmin = min(p0, p1), pmax = max(p0, p1);
      rel_row[tid] = 7 * pmin - (pmin * (pmin - 1)) / 2 + (pmax - pmin - 1);
    }
    __syncthreads();

    const int h = tid >> 7, c = tid & 127;        // half, float4-col
    const float4* x4 = (const float4*)(x + (size_t)blk * NC2 * D_DIM);
    float4 a = {0.f, 0.f, 0.f, 0.f};
    #pragma unroll
    for (int rp = 0; rp < NC2 / 2; ++rp) {        // clean streaming sum
      float4 v = x4[(rp * 2 + h) * 128 + c];
      a.x += v.x; a.y += v.y; a.z += v.z; a.w += v.w;
    }
    if (h) oddsum[c] = a;
    __syncthreads();
    if (!h) {
      float4 b = oddsum[c];
      bf16x4 o = { (bf16_t)(a.x + b.x), (bf16_t)(a.y + b.y),
                   (bf16_t)(a.z + b.z), (bf16_t)(a.w + b.w) };
      *(bf16x4*)(Sbf + (size_t)blk * D_DIM + c * 4) = o;
    }
    // gather pass: rows just streamed -> L1/L2 hot
    #pragma unroll
    for (int j = h; j < MAXREL; j += 2) {
      float4 v = x4[rel_row[j] * 128 + c];
      bf16x4 o = { (bf16_t)v.x, (bf16_t)v.y, (bf16_t)v.z, (bf16_t)v.w };
      *(bf16x4*)(Abf + (size_t)(blk * MAXREL + j) * D_DIM + c * 4) = o;
    }
  } else {
    __shared__ float tile[32 * 33];
    const int r = blk - B_SAMP;                   // 0..511
    const float* W  = (r & 256) ? Wnbr : Wself;
    bf16_t*     Wf  = (r & 256) ? Wnf  : Wsf;
    const int piece = r & 255;
    const int tstep = piece & 15, nblk = piece >> 4;
    const int k0 = tstep * 32, n0 = nblk * 32;
    const int tx = tid & 31, ty = tid >> 5;
    #pragma unroll
    for (int i = 0; i < 32; i += 8)
      tile[(ty + i) * 33 + tx] = W[(size_t)(k0 + ty + i) * D_DIM + n0 + tx];
    __syncthreads();
    // frag write: thread -> (cf_local, lane, elem-half); stores are
    // tid-contiguous 8B -> fully coalesced 2KB per block
    const int cfl = tid >> 7, rem = tid & 127;
    const int ll = rem >> 1, eh = rem & 1;
    const int kb = (ll >> 4) * 8 + eh * 4;        // k_local base
    const int nl = cfl * 16 + (ll & 15);          // n_local
    bf16x4 o = { (bf16_t)tile[(kb + 0) * 33 + nl], (bf16_t)tile[(kb + 1) * 33 + nl],
                 (bf16_t)tile[(kb + 2) * 33 + nl], (bf16_t)tile[(kb + 3) * 33 + nl] };
    const int cf = nblk * 2 + cfl;
    *(bf16x4*)(Wf + ((size_t)(cf * 16 + tstep) * 64 + ll) * 8 + eh * 4) = o;
  }
}

// --- K2: fused GEMM, A-LDS dbuf + frag-major B direct-to-reg ---------------
// Block (bx, by): 8 samples, out rows [bx*80, +80), cols [by*64, +64).
// A strips 0..4 = 80 rel rows (@Wself); strip 5 = 8 S rows dup (@Wnbr -> T).
// Wave w owns cols [by*64 + w*16, +16)  (cf = by*4 + w).
// A-LDS chunks (16B): LDS[row][c] = G[row][c ^ ((row>>1)&3)]  (involution).
#define SA_BYTES 6144              // 96 rows * 64 B

#define DO_STEP(BS, BN) do {                                                  \
    const bf16_t* aC = (const bf16_t*)(pool + cur * SA_BYTES);                \
    bf16x8 af[6];                                                             \
    _Pragma("unroll")                                                         \
    for (int s_ = 0; s_ < 6; ++s_)                                            \
      af[s_] = *(const bf16x8*)(aC + (s_ * 16 + lr) * 32 + xorc);             \
    _Pragma("unroll")                                                         \
    for (int s_ = 0; s_ < 5; ++s_)                                            \
      acc[s_] = __builtin_amdgcn_mfma_f32_16x16x32_bf16(af[s_], BS, acc[s_], 0, 0, 0); \
    acc[5] = __builtin_amdgcn_mfma_f32_16x16x32_bf16(af[5], BN, acc[5], 0, 0, 0); \
  } while (0)

__global__ __launch_bounds__(256, 5) void fused_gemm_kernel(
    const bf16_t* __restrict__ Abf, const bf16_t* __restrict__ Sbf,
    const bf16_t* __restrict__ Wsf, const bf16_t* __restrict__ Wnf,
    const float* __restrict__ bias, float* __restrict__ out)
{
  __shared__ __align__(16) unsigned char pool[2 * SA_BYTES];

  const int tid = threadIdx.x;
  const int w = tid >> 6, l = tid & 63;
  const int kg = l >> 4, lr = l & 15;
  const int n0w = blockIdx.y * 64 + w * 16;    // wave col base
  const int arow0 = blockIdx.x * 80;
  const int srow0 = blockIdx.x * 8;
  const int cf = blockIdx.y * 4 + w;           // wave's col-frag index

  // frag-major B streams: step t at +t*512 elems (1KB coalesced per wave)
  const bf16_t* pBs = Wsf + (size_t)cf * 16 * 512 + (size_t)l * 8;
  const bf16_t* pBn = Wnf + (size_t)cf * 16 * 512 + (size_t)l * 8;

  f32x4 acc[6] = {};

  // stage A slab (96 rows x 32 k = 384 x 16B chunks): w0,w1 -> 2; w2,w3 -> 1
  auto STAGE = [&](int bsel, int k0) {
    bf16_t* aB = (bf16_t*)(pool + bsel * SA_BYTES);
    #pragma unroll
    for (int r = 0; r < 2; ++r) {
      int slot = r * 4 + w;
      if (slot < 6) {
        int c = slot * 64 + l;
        int row = c >> 2, ch = c & 3;
        int sch = ch ^ ((row >> 1) & 3);
        const bf16_t* g = (row < 80)
            ? Abf + (size_t)(arow0 + row) * D_DIM + k0 + sch * 8
            : Sbf + (size_t)(srow0 + (row & 7)) * D_DIM + k0 + sch * 8;
        gload_lds16(g, aB + (size_t)c * 8);
      }
    }
  };

  bf16x8 bsX, bnX, bsY, bnY;
  STAGE(0, 0);
  bsX = *(const bf16x8*)(pBs);
  bnX = *(const bf16x8*)(pBn);
  __syncthreads();                               // drains stage + B t=0

  const int xorc = (kg ^ ((lr >> 1) & 3)) * 8;   // swizzled chunk -> elem off
  int cur = 0;
  #pragma unroll
  for (int t = 0; t < 16; t += 2) {
    // even step: compute cur with X; prefetch t+1 (A -> cur^1, B -> Y)
    if (t + 1 < 16) {
      STAGE(cur ^ 1, (t + 1) * 32);
      bsY = *(const bf16x8*)(pBs + (t + 1) * 512);
      bnY = *(const bf16x8*)(pBn + (t + 1) * 512);
    }
    DO_STEP(bsX, bnX);
    __syncthreads();                             // prefetch had full step to land
    cur ^= 1;

    // odd step: compute cur with Y; prefetch t+2 (A -> cur^1, B -> X)
    if (t + 2 < 16) {
      STAGE(cur ^ 1, (t + 2) * 32);
      bsX = *(const bf16x8*)(pBs + (t + 2) * 512);
      bnX = *(const bf16x8*)(pBn + (t + 2) * 512);
    }
    DO_STEP(bsY, bnY);
    __syncthreads();
    cur ^= 1;
  }

  // T tile -> per-wave LDS region (pool reuse; fenced by final barrier).
  // C/D layout: col = l&15, row = (l>>4)*4 + reg; strip-5 rows 8..15 dup 0..7.
  float* Tex = (float*)pool;                     // [4 waves][8][20]
  #pragma unroll
  for (int reg = 0; reg < 4; ++reg)
    Tex[(w * 8 + ((kg * 4 + reg) & 7)) * 20 + lr] = acc[5][reg];
  __syncthreads();

  const float bv = bias[n0w + lr];
  #pragma unroll
  for (int s = 0; s < 5; ++s) {
    #pragma unroll
    for (int reg = 0; reg < 4; ++reg) {
      int rloc = s * 16 + kg * 4 + reg;          // 0..79
      int ls = rloc / MAXREL;                    // local sample 0..7
      float v = acc[s][reg] + Tex[(w * 8 + ls) * 20 + lr] + bv;
      out[(size_t)(arow0 + rloc) * D_DIM + n0w + lr] = fmaxf(v, 0.0f);
    }
  }
}

extern "C" void kernel_launch(void* const* d_in, const int* in_sizes, int n_in,
                              void* d_out, int out_size, void* d_ws, size_t ws_size,
                              hipStream_t stream) {
  const float* x     = (const float*)d_in[0];   // [28672, 512]
  const float* Wself = (const float*)d_in[1];   // [512, 512]
  const float* Wnbr  = (const float*)d_in[2];   // [512, 512]
  const float* bias  = (const float*)d_in[3];   // [512]
  const int*   pairs = (const int*)d_in[5];     // [1024, 10, 2]

  char* ws = (char*)d_ws;
  size_t off = 0;
  bf16_t* Sbf = (bf16_t*)(ws + off); off += (size_t)B_SAMP * D_DIM * 2;
  bf16_t* Wsf = (bf16_t*)(ws + off); off += (size_t)D_DIM * D_DIM * 2;
  bf16_t* Wnf = (bf16_t*)(ws + off); off += (size_t)D_DIM * D_DIM * 2;
  bf16_t* Abf = (bf16_t*)(ws + off); off += (size_t)OUTROWS * D_DIM * 2;

  prep_kernel<<<B_SAMP + 512, 256, 0, stream>>>(
      x, Wself, Wnbr, pairs, Sbf, Abf, Wsf, Wnf);
  fused_gemm_kernel<<<dim3(OUTROWS / 80, D_DIM / 64), 256, 0, stream>>>(
      Abf, Sbf, Wsf, Wnf, bias, (float*)d_out);
}